// Round 11
// baseline (260.364 us; speedup 1.0000x reference)
//
#include <hip/hip_runtime.h>

// VQ-VAE vector quantizer, round 11: single-bf16 (hh-only) MFMA + exact rescan.
// R4/R8/R9 (no-spill MFMA) all ~96-103us with ~90% idle issue; every forced-occupancy
// attempt spilled (R5/R6/R10). Surviving lever: halve per-wave serial work. Distances use
// ONLY xh.eh (bf16 hi parts): per 32-code group 4 B-loads + 1 hsq + 4 MFMA (R8: 8+1+12),
// B-traffic/CU halves. hh-only v-error std ~0.011 (6 sigma=0.066); EPSGAP=0.10 (~9 sigma)
// flags all at-risk points for exact-fp32 full rescan (few %, one wave per point).
// Skeleton = R8: NPB=128, 512 blocks, launch_bounds(256,2) (never spills), 32x32x16 tiles,
// C/D row map row=(r&3)+8*(r>>2)+4*(lane>>5), exact streaming top-2 per lane.
// out (fp32 concat): [ loss(1) | quantized NCHW (4194304) | indices as float (65536) ]

#define DIMS   64
#define HW     4096
#define NPTS   65536
#define NCODES 1024
#define NPB    128
#define QOFF   1
#define IOFF   (1 + NPTS * DIMS)
#define EPSGAP 0.10f

typedef unsigned int uint;
typedef unsigned short ushort;
typedef unsigned long long ull;
typedef __attribute__((ext_vector_type(8))) short short8;
typedef __attribute__((ext_vector_type(16))) float f32x16;

__device__ __forceinline__ ushort bf16_rne(float f) {
    uint u = __float_as_uint(f);
    uint r = u + 0x7FFFu + ((u >> 16) & 1u);
    return (ushort)(r >> 16);
}

// ---- prep: emb fp32 -> Eh bf16 [1024][64], hsq = 0.5||e||^2, zero out[0]
__global__ void vq_prep(const float* __restrict__ emb, ushort* __restrict__ Eh,
                        float* __restrict__ hsq, float* __restrict__ out)
{
    const int t = blockIdx.x * 256 + threadIdx.x;      // 0..16383, one float4 each
    if (t == 0) out[0] = 0.f;
    float4 v = ((const float4*)emb)[t];
    uint2 hp;
    hp.x = (uint)bf16_rne(v.x) | ((uint)bf16_rne(v.y) << 16);
    hp.y = (uint)bf16_rne(v.z) | ((uint)bf16_rne(v.w) << 16);
    *(uint2*)(Eh + (size_t)t * 4) = hp;
    if (t < NCODES) {
        const float4* r = (const float4*)(emb + (size_t)t * DIMS);
        float s = 0.f;
        #pragma unroll
        for (int i = 0; i < 16; ++i) {
            float4 e = r[i];
            s = fmaf(e.x, e.x, s); s = fmaf(e.y, e.y, s);
            s = fmaf(e.z, e.z, s); s = fmaf(e.w, e.w, s);
        }
        hsq[t] = 0.5f * s;
    }
}

__launch_bounds__(256, 2)
__global__ void vq_main(const float* __restrict__ in, const float* __restrict__ emb,
                        const ushort* __restrict__ Ehw, const float* __restrict__ hsqw,
                        float* __restrict__ out)
{
    __shared__ float sv1[NPB];
    __shared__ float sv2[NPB];
    __shared__ int   si1[NPB];
    __shared__ ull   msk[2];
    __shared__ int   lst[1 + NPB];
    __shared__ float lred[4];

    const int tid = threadIdx.x;
    const int lane = tid & 63, w = tid >> 6;
    const int nn = lane & 31;                          // row (A) / col (B) within 32
    const int h  = lane >> 5;                          // k-half selector
    const int n0 = blockIdx.x * NPB;
    const int b = n0 >> 12, off = n0 & 4095;           // 128 | 4096: never crosses a batch
    const float* xbase = in + (size_t)b * (DIMS * HW) + off;

    // ---- A fragments: wave's 32 points, hi bf16 only; k = ks*16 + 8h + j
    short8 Ah[4];
    {
        const int p = w * 32 + nn;
        #pragma unroll
        for (int ks = 0; ks < 4; ++ks) {
            union { ushort u[8]; short8 v; } th;
            #pragma unroll
            for (int j = 0; j < 8; ++j)
                th.u[j] = bf16_rne(xbase[(ks * 16 + h * 8 + j) * HW + p]);
            Ah[ks] = th.v;
        }
    }

    float v1s[16], v2s[16]; int i1s[16];
    #pragma unroll
    for (int r = 0; r < 16; ++r) { v1s[r] = 1e30f; v2s[r] = 1e30f; i1s[r] = 0; }

    // ---- K-loop: 32 groups of 32 codes; one 32x32 tile = 4 MFMA (hh only, K=64)
    #pragma unroll 2
    for (int g = 0; g < 32; ++g) {
        const int ca = g * 32 + nn;                    // this lane's code id
        const ushort* eb = Ehw + (size_t)ca * 64 + h * 8;
        short8 Bh[4];
        #pragma unroll
        for (int ks = 0; ks < 4; ++ks) Bh[ks] = *(const short8*)(eb + ks * 16);
        const float ha = hsqw[ca];
        f32x16 acc = {0.f,0.f,0.f,0.f,0.f,0.f,0.f,0.f,0.f,0.f,0.f,0.f,0.f,0.f,0.f,0.f};
        #pragma unroll
        for (int ks = 0; ks < 4; ++ks)
            acc = __builtin_amdgcn_mfma_f32_32x32x16_bf16(Ah[ks], Bh[ks], acc, 0, 0, 0);
        #pragma unroll
        for (int r = 0; r < 16; ++r) {                 // r -> point row (fixed lane->code)
            float d = ha - acc[r];
            v2s[r] = fminf(v2s[r], fmaxf(d, v1s[r])); // exact streaming 2nd-min
            bool c2 = d < v1s[r];                      // strict: ascending g keeps lowest idx
            i1s[r] = c2 ? ca : i1s[r];
            v1s[r] = fminf(d, v1s[r]);
        }
    }

    // ---- merge across the 32 code-lanes (both k-halves of a point share a half-wave)
    #pragma unroll
    for (int st = 1; st < 32; st <<= 1) {
        #pragma unroll
        for (int r = 0; r < 16; ++r) {
            float ov1 = __shfl_xor(v1s[r], st);
            float ov2 = __shfl_xor(v2s[r], st);
            int   oi1 = __shfl_xor(i1s[r], st);
            v2s[r] = fminf(fminf(v2s[r], ov2), fmaxf(v1s[r], ov1));
            bool c = (ov1 < v1s[r]) || (ov1 == v1s[r] && oi1 < i1s[r]);
            if (c) i1s[r] = oi1;
            v1s[r] = fminf(v1s[r], ov1);
        }
    }
    if (nn == 0) {                                     // lanes 0 and 32 hold 16 rows each
        #pragma unroll
        for (int r = 0; r < 16; ++r) {
            const int row = (r & 3) + 8 * (r >> 2) + 4 * h;
            const int p = w * 32 + row;
            sv1[p] = v1s[r]; si1[p] = i1s[r]; sv2[p] = v2s[r];
        }
    }
    __syncthreads();

    // ---- flag near-ties (waves 0,1 cover points 0..127); EPSGAP covers hh-only error
    {
        bool f = (tid < NPB) && ((sv2[tid] - sv1[tid]) < EPSGAP);
        ull bm = __ballot(f);
        if (lane == 0 && w < 2) msk[w] = bm;
    }
    __syncthreads();
    if (tid == 0) {
        int c = 0;
        ull m0 = msk[0];
        while (m0) { lst[1 + c++] = __ffsll(m0) - 1; m0 &= m0 - 1; }
        ull m1 = msk[1];
        while (m1) { lst[1 + c++] = 64 + (__ffsll(m1) - 1); m1 &= m1 - 1; }
        lst[0] = c;
    }
    __syncthreads();

    // ---- exact fp32 rescan, one wave per flagged point (all 1024 codes)
    const int cnt = lst[0];
    const float4* e4 = (const float4*)emb;
    for (int it = w; it < cnt; it += 4) {
        const int p = lst[1 + it];
        float xv = xbase[lane * HW + p];               // lane d holds x_d (exact fp32)
        float bv = 1e30f; int bk = 0;
        #pragma unroll
        for (int half = 0; half < 2; ++half) {
            float dacc[8];
            #pragma unroll
            for (int j = 0; j < 8; ++j) dacc[j] = 0.f;
            for (int d4 = 0; d4 < 16; ++d4) {
                float x0 = __shfl(xv, d4 * 4 + 0), x1 = __shfl(xv, d4 * 4 + 1);
                float x2 = __shfl(xv, d4 * 4 + 2), x3 = __shfl(xv, d4 * 4 + 3);
                #pragma unroll
                for (int j = 0; j < 8; ++j) {
                    const int k = lane + 64 * (half * 8 + j);
                    float4 e = e4[k * 16 + d4];
                    dacc[j] = fmaf(x0, e.x, dacc[j]); dacc[j] = fmaf(x1, e.y, dacc[j]);
                    dacc[j] = fmaf(x2, e.z, dacc[j]); dacc[j] = fmaf(x3, e.w, dacc[j]);
                }
            }
            #pragma unroll
            for (int j = 0; j < 8; ++j) {              // ascending k per lane: first-min kept
                const int k = lane + 64 * (half * 8 + j);
                float v = hsqw[k] - dacc[j];
                if (v < bv) { bv = v; bk = k; }
            }
        }
        #pragma unroll
        for (int st = 32; st; st >>= 1) {              // 64-wide (v, k) argmin, k tie-break
            float ov = __shfl_xor(bv, st);
            int   ok = __shfl_xor(bk, st);
            if (ov < bv || (ov == bv && ok < bk)) { bv = ov; bk = ok; }
        }
        if (lane == 0) si1[p] = bk;
    }
    __syncthreads();

    // ---- final: indices, quantized gather-write, loss — all 256 threads (32 dims each)
    {
        const int p = tid & 127, dg = tid >> 7;
        const int bi = si1[p];
        if (dg == 0) out[IOFF + n0 + p] = (float)bi;
        const float* e = emb + (size_t)bi * DIMS;
        const float* xp = xbase + p;
        float* oq = out + QOFF + (size_t)b * (DIMS * HW) + off + p;
        float ls = 0.f;
        #pragma unroll
        for (int d0 = 0; d0 < 32; ++d0) {
            const int d = dg * 32 + d0;
            float ev = e[d];
            float xv = xp[d * HW];
            float df = ev - xv;
            ls = fmaf(df, df, ls);
            oq[d * HW] = ev;                           // coalesced across point-threads
        }
        #pragma unroll
        for (int st = 32; st; st >>= 1) ls += __shfl_down(ls, st);
        if (lane == 0) lred[w] = ls;
    }
    __syncthreads();
    if (tid == 0) {
        float s = lred[0] + lred[1] + lred[2] + lred[3];
        atomicAdd(out, s * (0.25f / (float)(NPTS * DIMS)));
    }
}

extern "C" void kernel_launch(void* const* d_in, const int* in_sizes, int n_in,
                              void* d_out, int out_size, void* d_ws, size_t ws_size,
                              hipStream_t stream) {
    const float* in  = (const float*)d_in[0];
    const float* emb = (const float*)d_in[1];
    float* out = (float*)d_out;
    ushort* Eh  = (ushort*)d_ws;                       // 131072 B
    float*  hsq = (float*)((char*)d_ws + 131072);      // 4096 B
    (void)in_sizes; (void)n_in; (void)out_size; (void)ws_size;

    vq_prep<<<64, 256, 0, stream>>>(emb, Eh, hsq, out);   // also zeroes out[0]
    vq_main<<<NPTS / NPB, 256, 0, stream>>>(in, emb, Eh, hsq, out);
}

// Round 12
// 155.089 us; speedup vs baseline: 1.6788x; 1.6788x over previous
//
#include <hip/hip_runtime.h>

// VQ-VAE vector quantizer, round 12: split-bf16 MFMA with explicit register double-buffer.
// Diagnosis: MFMA kernels run in a reduced clock state (~1 GHz; back-solved from R9's
// VALUBusy vs issue count) AND the K-loop is serial per 32-code group (B-fetch ~200-400cyc
// -> MFMA -> track) with zero prefetch distance at 56-68 VGPR. Fix: unroll-by-2 K-loop with
// two static B-buffer sets; loadB(g+1) issues before compute(g) (~350 issue-cyc of cover).
// launch_bounds(256,2): 256-VGPR cap fits the ~210-reg live set without spilling.
// 32x32x16 tiles, 12 MFMA/group in 2 chains (hh 4-deep; hl+lh 8-deep). Exact streaming
// top-2; near-ties (gap < 1e-3 vs ~1e-4 split error) rescanned exactly in fp32.
// out (fp32 concat): [ loss(1) | quantized NCHW (4194304) | indices as float (65536) ]

#define DIMS   64
#define HW     4096
#define NPTS   65536
#define NCODES 1024
#define NPB    128
#define QOFF   1
#define IOFF   (1 + NPTS * DIMS)
#define EPSGAP 1.0e-3f

typedef unsigned int uint;
typedef unsigned short ushort;
typedef unsigned long long ull;
typedef __attribute__((ext_vector_type(8))) short short8;
typedef __attribute__((ext_vector_type(16))) float f32x16;

__device__ __forceinline__ ushort bf16_rne(float f) {
    uint u = __float_as_uint(f);
    uint r = u + 0x7FFFu + ((u >> 16) & 1u);
    return (ushort)(r >> 16);
}
__device__ __forceinline__ float bf16f(ushort h) { return __uint_as_float(((uint)h) << 16); }

// ---- prep: emb fp32 -> {Eh, El bf16 [1024][64]}, hsq = 0.5||e||^2, zero out[0]
__global__ void vq_prep(const float* __restrict__ emb, ushort* __restrict__ Eh,
                        ushort* __restrict__ El, float* __restrict__ hsq,
                        float* __restrict__ out)
{
    const int t = blockIdx.x * 256 + threadIdx.x;      // 0..16383, one float4 each
    if (t == 0) out[0] = 0.f;
    float4 v = ((const float4*)emb)[t];
    ushort h0 = bf16_rne(v.x), h1 = bf16_rne(v.y), h2 = bf16_rne(v.z), h3 = bf16_rne(v.w);
    ushort l0 = bf16_rne(v.x - bf16f(h0)), l1 = bf16_rne(v.y - bf16f(h1));
    ushort l2 = bf16_rne(v.z - bf16f(h2)), l3 = bf16_rne(v.w - bf16f(h3));
    uint2 hp, lp;
    hp.x = (uint)h0 | ((uint)h1 << 16); hp.y = (uint)h2 | ((uint)h3 << 16);
    lp.x = (uint)l0 | ((uint)l1 << 16); lp.y = (uint)l2 | ((uint)l3 << 16);
    *(uint2*)(Eh + (size_t)t * 4) = hp;
    *(uint2*)(El + (size_t)t * 4) = lp;
    if (t < NCODES) {
        const float4* r = (const float4*)(emb + (size_t)t * DIMS);
        float s = 0.f;
        #pragma unroll
        for (int i = 0; i < 16; ++i) {
            float4 e = r[i];
            s = fmaf(e.x, e.x, s); s = fmaf(e.y, e.y, s);
            s = fmaf(e.z, e.z, s); s = fmaf(e.w, e.w, s);
        }
        hsq[t] = 0.5f * s;
    }
}

__launch_bounds__(256, 2)
__global__ void vq_main(const float* __restrict__ in, const float* __restrict__ emb,
                        const ushort* __restrict__ Ehw, const ushort* __restrict__ Elw,
                        const float* __restrict__ hsqw, float* __restrict__ out)
{
    __shared__ float sv1[NPB];
    __shared__ float sv2[NPB];
    __shared__ int   si1[NPB];
    __shared__ ull   msk[2];
    __shared__ int   lst[1 + NPB];
    __shared__ float lred[4];

    const int tid = threadIdx.x;
    const int lane = tid & 63, w = tid >> 6;
    const int nn = lane & 31;                          // row (A) / col (B) within 32
    const int h  = lane >> 5;                          // k-half selector
    const int n0 = blockIdx.x * NPB;
    const int b = n0 >> 12, off = n0 & 4095;           // 128 | 4096: never crosses a batch
    const float* xbase = in + (size_t)b * (DIMS * HW) + off;

    // ---- A fragments: wave's 32 points, hi+lo bf16; k = ks*16 + 8h + j
    short8 Ah[4], Al[4];
    {
        const int p = w * 32 + nn;
        #pragma unroll
        for (int ks = 0; ks < 4; ++ks) {
            union { ushort u[8]; short8 v; } th, tl;
            #pragma unroll
            for (int j = 0; j < 8; ++j) {
                float x = xbase[(ks * 16 + h * 8 + j) * HW + p];
                ushort hh = bf16_rne(x);
                th.u[j] = hh;
                tl.u[j] = bf16_rne(x - bf16f(hh));
            }
            Ah[ks] = th.v; Al[ks] = tl.v;
        }
    }

    float v1s[16], v2s[16]; int i1s[16];
    #pragma unroll
    for (int r = 0; r < 16; ++r) { v1s[r] = 1e30f; v2s[r] = 1e30f; i1s[r] = 0; }

    auto loadB = [&](int g, short8 (&BH)[4], short8 (&BL)[4], float& HA) {
        const int ca = g * 32 + nn;
        const ushort* eb = Ehw + (size_t)ca * 64 + h * 8;
        const ushort* lb = Elw + (size_t)ca * 64 + h * 8;
        #pragma unroll
        for (int ks = 0; ks < 4; ++ks) {
            BH[ks] = *(const short8*)(eb + ks * 16);
            BL[ks] = *(const short8*)(lb + ks * 16);
        }
        HA = hsqw[ca];
    };

    auto compute = [&](int g, const short8 (&BH)[4], const short8 (&BL)[4], float HA) {
        f32x16 a1 = {0.f,0.f,0.f,0.f,0.f,0.f,0.f,0.f,0.f,0.f,0.f,0.f,0.f,0.f,0.f,0.f};
        f32x16 a2 = {0.f,0.f,0.f,0.f,0.f,0.f,0.f,0.f,0.f,0.f,0.f,0.f,0.f,0.f,0.f,0.f};
        #pragma unroll
        for (int ks = 0; ks < 4; ++ks)                 // chain 1: hh (4-deep)
            a1 = __builtin_amdgcn_mfma_f32_32x32x16_bf16(Ah[ks], BH[ks], a1, 0, 0, 0);
        #pragma unroll
        for (int ks = 0; ks < 4; ++ks)                 // chain 2a: hl
            a2 = __builtin_amdgcn_mfma_f32_32x32x16_bf16(Ah[ks], BL[ks], a2, 0, 0, 0);
        #pragma unroll
        for (int ks = 0; ks < 4; ++ks)                 // chain 2b: lh (same acc, 8-deep)
            a2 = __builtin_amdgcn_mfma_f32_32x32x16_bf16(Al[ks], BH[ks], a2, 0, 0, 0);
        const int ca = g * 32 + nn;
        #pragma unroll
        for (int r = 0; r < 16; ++r) {                 // r -> point row (fixed lane->code)
            float d = HA - (a1[r] + a2[r]);
            v2s[r] = fminf(v2s[r], fmaxf(d, v1s[r]));  // exact streaming 2nd-min
            bool c2 = d < v1s[r];                      // strict: ascending g keeps lowest idx
            i1s[r] = c2 ? ca : i1s[r];
            v1s[r] = fminf(d, v1s[r]);
        }
    };

    // ---- K-loop: 32 groups of 32 codes, register-double-buffered (prefetch distance 1)
    short8 BhA[4], BlA[4], BhB[4], BlB[4];
    float haA, haB;
    loadB(0, BhA, BlA, haA);
    for (int g = 0; g < 32; g += 2) {
        loadB(g + 1, BhB, BlB, haB);                   // in flight across compute(g)
        compute(g, BhA, BlA, haA);
        if (g + 2 < 32) loadB(g + 2, BhA, BlA, haA);   // in flight across compute(g+1)
        compute(g + 1, BhB, BlB, haB);
    }

    // ---- merge across the 32 code-lanes (both k-halves of a point share a half-wave)
    #pragma unroll
    for (int st = 1; st < 32; st <<= 1) {
        #pragma unroll
        for (int r = 0; r < 16; ++r) {
            float ov1 = __shfl_xor(v1s[r], st);
            float ov2 = __shfl_xor(v2s[r], st);
            int   oi1 = __shfl_xor(i1s[r], st);
            v2s[r] = fminf(fminf(v2s[r], ov2), fmaxf(v1s[r], ov1));
            bool c = (ov1 < v1s[r]) || (ov1 == v1s[r] && oi1 < i1s[r]);
            if (c) i1s[r] = oi1;
            v1s[r] = fminf(v1s[r], ov1);
        }
    }
    if (nn == 0) {                                     // lanes 0 and 32 hold 16 rows each
        #pragma unroll
        for (int r = 0; r < 16; ++r) {
            const int row = (r & 3) + 8 * (r >> 2) + 4 * h;
            const int p = w * 32 + row;
            sv1[p] = v1s[r]; si1[p] = i1s[r]; sv2[p] = v2s[r];
        }
    }
    __syncthreads();

    // ---- flag near-ties (waves 0,1 cover points 0..127)
    {
        bool f = (tid < NPB) && ((sv2[tid] - sv1[tid]) < EPSGAP);
        ull bm = __ballot(f);
        if (lane == 0 && w < 2) msk[w] = bm;
    }
    __syncthreads();
    if (tid == 0) {
        int c = 0;
        ull m0 = msk[0];
        while (m0) { lst[1 + c++] = __ffsll(m0) - 1; m0 &= m0 - 1; }
        ull m1 = msk[1];
        while (m1) { lst[1 + c++] = 64 + (__ffsll(m1) - 1); m1 &= m1 - 1; }
        lst[0] = c;
    }
    __syncthreads();

    // ---- exact fp32 rescan, one wave per flagged point (rare: gap < 1e-3)
    const int cnt = lst[0];
    const float4* e4 = (const float4*)emb;
    for (int it = w; it < cnt; it += 4) {
        const int p = lst[1 + it];
        float xv = xbase[lane * HW + p];               // lane d holds x_d (exact fp32)
        float bv = 1e30f; int bk = 0;
        #pragma unroll
        for (int half = 0; half < 2; ++half) {
            float dacc[8];
            #pragma unroll
            for (int j = 0; j < 8; ++j) dacc[j] = 0.f;
            for (int d4 = 0; d4 < 16; ++d4) {
                float x0 = __shfl(xv, d4 * 4 + 0), x1 = __shfl(xv, d4 * 4 + 1);
                float x2 = __shfl(xv, d4 * 4 + 2), x3 = __shfl(xv, d4 * 4 + 3);
                #pragma unroll
                for (int j = 0; j < 8; ++j) {
                    const int k = lane + 64 * (half * 8 + j);
                    float4 e = e4[k * 16 + d4];
                    dacc[j] = fmaf(x0, e.x, dacc[j]); dacc[j] = fmaf(x1, e.y, dacc[j]);
                    dacc[j] = fmaf(x2, e.z, dacc[j]); dacc[j] = fmaf(x3, e.w, dacc[j]);
                }
            }
            #pragma unroll
            for (int j = 0; j < 8; ++j) {              // ascending k per lane: first-min kept
                const int k = lane + 64 * (half * 8 + j);
                float v = hsqw[k] - dacc[j];
                if (v < bv) { bv = v; bk = k; }
            }
        }
        #pragma unroll
        for (int st = 32; st; st >>= 1) {              // 64-wide (v, k) argmin, k tie-break
            float ov = __shfl_xor(bv, st);
            int   ok = __shfl_xor(bk, st);
            if (ov < bv || (ov == bv && ok < bk)) { bv = ov; bk = ok; }
        }
        if (lane == 0) si1[p] = bk;
    }
    __syncthreads();

    // ---- final: indices, quantized gather-write, loss — all 256 threads (32 dims each)
    {
        const int p = tid & 127, dg = tid >> 7;
        const int bi = si1[p];
        if (dg == 0) out[IOFF + n0 + p] = (float)bi;
        const float* e = emb + (size_t)bi * DIMS;
        const float* xp = xbase + p;
        float* oq = out + QOFF + (size_t)b * (DIMS * HW) + off + p;
        float ls = 0.f;
        #pragma unroll
        for (int d0 = 0; d0 < 32; ++d0) {
            const int d = dg * 32 + d0;
            float ev = e[d];
            float xv = xp[d * HW];
            float df = ev - xv;
            ls = fmaf(df, df, ls);
            oq[d * HW] = ev;                           // coalesced across point-threads
        }
        #pragma unroll
        for (int st = 32; st; st >>= 1) ls += __shfl_down(ls, st);
        if (lane == 0) lred[w] = ls;
    }
    __syncthreads();
    if (tid == 0) {
        float s = lred[0] + lred[1] + lred[2] + lred[3];
        atomicAdd(out, s * (0.25f / (float)(NPTS * DIMS)));
    }
}

extern "C" void kernel_launch(void* const* d_in, const int* in_sizes, int n_in,
                              void* d_out, int out_size, void* d_ws, size_t ws_size,
                              hipStream_t stream) {
    const float* in  = (const float*)d_in[0];
    const float* emb = (const float*)d_in[1];
    float* out = (float*)d_out;
    ushort* Eh  = (ushort*)d_ws;                       // 131072 B
    ushort* El  = (ushort*)((char*)d_ws + 131072);     // 131072 B
    float*  hsq = (float*)((char*)d_ws + 262144);      // 4096 B
    (void)in_sizes; (void)n_in; (void)out_size; (void)ws_size;

    vq_prep<<<64, 256, 0, stream>>>(emb, Eh, El, hsq, out);   // also zeroes out[0]
    vq_main<<<NPTS / NPB, 256, 0, stream>>>(in, emb, Eh, El, hsq, out);
}